// Round 3
// baseline (147477.258 us; speedup 1.0000x reference)
//
#include <hip/hip_runtime.h>
#include <math.h>

namespace {
constexpr int T = 512, B = 64, D = 512, H = 512;
constexpr int WROW = 1028;   // 1024 k + 4 pad
constexpr int CHK  = 128;    // k per staged chunk
constexpr int XROW = 132;    // CHK + 4 pad
constexpr int WLDS = 16 * WROW;
constexpr int XBUF = B * XROW;
constexpr int PROW = 36;     // 8 kq * 4 gates + 4 pad
constexpr int NBLK = 128;    // blocks per direction
}

__global__ __launch_bounds__(256) void ws_zero(float* p, int n) {
  int i = blockIdx.x * 256 + threadIdx.x;
  if (i < n) p[i] = 0.f;
}

// Persistent bi-LSTM. grid=256 (1 block/CU): dir(2) x jtile(128, 4 j each).
// block=1024 threads (16 waves). Weights in LDS for the whole kernel; c,h in
// finisher registers; per-direction hand-rolled barrier; x-part of step s+1
// computed between barrier arrive and wait.
__global__ __launch_bounds__(1024, 4) void bilstm_persistent(
    const float* __restrict__ x, const float* __restrict__ mask,
    const float* __restrict__ WihF, const float* __restrict__ WhhF,
    const float* __restrict__ bihF, const float* __restrict__ bhhF,
    const float* __restrict__ WihR, const float* __restrict__ WhhR,
    const float* __restrict__ bihR, const float* __restrict__ bhhR,
    float* __restrict__ hbuf, int* __restrict__ cnt, float* __restrict__ out)
{
  __shared__ float smem[WLDS + 2 * XBUF];   // 133,376 B
  float* const wlds = smem;
  float* const xh   = smem + WLDS;
  float* const P    = xh;                   // overlay, used between phases

  const int tid = threadIdx.x;
  const int dir = (int)blockIdx.x >> 7;
  const int j0  = ((int)blockIdx.x & 127) * 4;

  const float* __restrict__ Wih = dir ? WihR : WihF;
  const float* __restrict__ Whh = dir ? WhhR : WhhF;
  const float* __restrict__ bih = dir ? bihR : bihF;
  const float* __restrict__ bhh = dir ? bhhR : bhhF;

  // compute role: thread = (jjc 4, bq 32, kq 8); owns b=bq+32i (i=0,1),
  // j=j0+jjc, 4 gates, k-slice kq*16..+15 of each 128-chunk.
  const int jjc = tid & 3, bq = (tid >> 2) & 31, kq = tid >> 7;
  // stage role: 2 float4 per thread
  const int sb = tid >> 5, sf4 = tid & 31;
  // finisher role (tid<256): v = fb*4+fjj == tid within wave (conflict-free)
  const int fb = (tid >> 2) & 63, fjj = tid & 3;

  const float* hRead[2] = {hbuf + (size_t)dir * B * H,
                           hbuf + (size_t)(2 + dir) * B * H};

  float4 gx0, gx1;
  auto issue = [&](const float* base, int koff) {
    const float* s0 = base + (size_t)sb * 512 + koff + sf4 * 4;
    gx0 = *(const float4*)s0;
    gx1 = *(const float4*)(s0 + 32 * 512);
  };
  auto write_chunk = [&](int pb) {
    float* d0 = xh + pb * XBUF + sb * XROW + sf4 * 4;
    *(float4*)d0 = gx0;
    *(float4*)(d0 + 32 * XROW) = gx1;
  };
  auto compute_chunk = [&](int pb, int c, float (*acc)[4]) {
    const float* wb = wlds + jjc * WROW + c * CHK + kq * 16;
    const float* xb = xh + pb * XBUF + kq * 16;
    #pragma unroll
    for (int k4 = 0; k4 < 4; ++k4) {
      const int ko = k4 * 4;
      float4 w0 = *(const float4*)(wb + 0 * 4 * WROW + ko);
      float4 w1 = *(const float4*)(wb + 1 * 4 * WROW + ko);
      float4 w2 = *(const float4*)(wb + 2 * 4 * WROW + ko);
      float4 w3 = *(const float4*)(wb + 3 * 4 * WROW + ko);
      #pragma unroll
      for (int i = 0; i < 2; ++i) {
        float4 hv = *(const float4*)(xb + (bq + 32 * i) * XROW + ko);
        acc[i][0] += hv.x * w0.x + hv.y * w0.y + hv.z * w0.z + hv.w * w0.w;
        acc[i][1] += hv.x * w1.x + hv.y * w1.y + hv.z * w1.z + hv.w * w1.w;
        acc[i][2] += hv.x * w2.x + hv.y * w2.y + hv.z * w2.z + hv.w * w2.w;
        acc[i][3] += hv.x * w3.x + hv.y * w3.y + hv.z * w3.z + hv.w * w3.w;
      }
    }
  };

  // ---- weights -> LDS once; first x chunk issued first to overlap
  const int t0 = dir ? T - 1 : 0;
  issue(x + (size_t)t0 * B * D, 0);
  for (int idx = tid; idx < 16 * 256; idx += 1024) {
    const int row = idx >> 8, f4c = idx & 255;
    const int g = row >> 2, jj = row & 3, k = f4c * 4;
    const float* src = (k < D)
        ? Wih + (size_t)(g * H + j0 + jj) * D + k
        : Whh + (size_t)(g * H + j0 + jj) * H + (k - D);
    *(float4*)&wlds[row * WROW + k] = *(const float4*)src;
  }

  float bs0 = 0.f, bs1 = 0.f, bs2 = 0.f, bs3 = 0.f, cReg = 0.f, hReg = 0.f;
  if (tid < 256) {
    bs0 = bih[0 * H + j0 + fjj] + bhh[0 * H + j0 + fjj];
    bs1 = bih[1 * H + j0 + fjj] + bhh[1 * H + j0 + fjj];
    bs2 = bih[2 * H + j0 + fjj] + bhh[2 * H + j0 + fjj];
    bs3 = bih[3 * H + j0 + fjj] + bhh[3 * H + j0 + fjj];
  }

  // ---- prologue: x-part for step 0
  float accx[2][4] = {{0.f, 0.f, 0.f, 0.f}, {0.f, 0.f, 0.f, 0.f}};
  for (int xc = 0; xc < 4; ++xc) {
    __syncthreads();
    write_chunk(xc & 1);
    if (xc < 3) issue(x + (size_t)t0 * B * D, (xc + 1) * CHK);
    __syncthreads();
    compute_chunk(xc & 1, xc, accx);
  }
  issue(hRead[0], 0);   // h(0) = zeros from ws_zero, visible at kernel start

  for (int s = 0; s < T; ++s) {
    const int t = dir ? (T - 1 - s) : s;
    float mval = 0.f;
    if (tid < 256) mval = mask[(size_t)t * B + fb];   // prefetch early

    float acc[2][4];
    #pragma unroll
    for (int i = 0; i < 2; ++i)
      #pragma unroll
      for (int g = 0; g < 4; ++g) acc[i][g] = accx[i][g];

    // ---- h-phase (critical path): chunks c=4..7
    const float* hb = hRead[s & 1];
    for (int hc = 0; hc < 4; ++hc) {
      __syncthreads();
      write_chunk(hc & 1);
      if (hc < 3) issue(hb, (hc + 1) * CHK);
      else if (s + 1 < T)
        issue(x + (size_t)(dir ? T - 2 - s : s + 1) * B * D, 0);
      __syncthreads();
      compute_chunk(hc & 1, 4 + hc, acc);
    }

    // ---- partial reduce via LDS (float4 gate-groups, conflict-free)
    __syncthreads();
    #pragma unroll
    for (int i = 0; i < 2; ++i) {
      const int v = (bq + 32 * i) * 4 + jjc;
      float4 pv = {acc[i][0], acc[i][1], acc[i][2], acc[i][3]};
      *(float4*)&P[v * PROW + kq * 4] = pv;
    }
    __syncthreads();

    // ---- finisher: gates, cell update, h/out stores
    if (tid < 256) {
      const float* pr = P + (fb * 4 + fjj) * PROW;
      float g0 = bs0, g1 = bs1, g2 = bs2, g3 = bs3;
      #pragma unroll
      for (int q = 0; q < 8; ++q) {
        float4 a = *(const float4*)(pr + q * 4);
        g0 += a.x; g1 += a.y; g2 += a.z; g3 += a.w;
      }
      const float ig = 1.f / (1.f + expf(-g0));
      const float fg = 1.f / (1.f + expf(-g1));
      const float gg = tanhf(g2);
      const float og = 1.f / (1.f + expf(-g3));
      const float cNew = fg * cReg + ig * gg;
      const float hNew = og * tanhf(cNew);
      hReg = hNew * mval + hReg * (1.f - mval);
      cReg = cNew * mval + cReg * (1.f - mval);
      hbuf[((size_t)(((s + 1) & 1) * 2 + dir) * B + fb) * H + j0 + fjj] = hReg;
      __threadfence();   // release h before arrive; out store can trail
      out[((size_t)t * B + fb) * (2 * H) + (size_t)dir * H + j0 + fjj] = hReg;
    }
    __syncthreads();

    if (s + 1 < T) {
      if (tid == 0) atomicAdd(&cnt[dir], 1);   // arrive ASAP

      // ---- x-phase for step s+1, overlapped with barrier latency
      #pragma unroll
      for (int i = 0; i < 2; ++i)
        #pragma unroll
        for (int g = 0; g < 4; ++g) accx[i][g] = 0.f;
      const int tn = dir ? (T - 2 - s) : (s + 1);
      for (int xc = 0; xc < 4; ++xc) {
        __syncthreads();
        write_chunk(xc & 1);
        if (xc < 3) issue(x + (size_t)tn * B * D, (xc + 1) * CHK);
        __syncthreads();
        compute_chunk(xc & 1, xc, accx);
      }

      // ---- barrier wait (per-direction)
      if (tid == 0) {
        const int target = NBLK * (s + 1);
        while (__hip_atomic_load(&cnt[dir], __ATOMIC_RELAXED,
                                 __HIP_MEMORY_SCOPE_AGENT) < target)
          __builtin_amdgcn_s_sleep(1);
        __threadfence();   // acquire: invalidate L1/L2 before reading h(s+1)
      }
      __syncthreads();
      issue(hRead[(s + 1) & 1], 0);
    }
  }
}

extern "C" void kernel_launch(void* const* d_in, const int* in_sizes, int n_in,
                              void* d_out, int out_size, void* d_ws, size_t ws_size,
                              hipStream_t stream) {
  const float* x    = (const float*)d_in[0];
  const float* mask = (const float*)d_in[1];
  const float* WihF = (const float*)d_in[2];
  const float* WhhF = (const float*)d_in[3];
  const float* bihF = (const float*)d_in[4];
  const float* bhhF = (const float*)d_in[5];
  const float* WihR = (const float*)d_in[6];
  const float* WhhR = (const float*)d_in[7];
  const float* bihR = (const float*)d_in[8];
  const float* bhhR = (const float*)d_in[9];
  float* hbuf = (float*)d_ws;                       // 2 bufs x 2 dirs x B x H
  int*   cnt  = (int*)((float*)d_ws + 2 * 2 * B * H);
  float* outp = (float*)d_out;

  int nz = 2 * 2 * B * H + 16;                      // hbuf + counters
  ws_zero<<<(nz + 255) / 256, 256, 0, stream>>>((float*)d_ws, nz);

  void* args[] = {(void*)&x, (void*)&mask,
                  (void*)&WihF, (void*)&WhhF, (void*)&bihF, (void*)&bhhF,
                  (void*)&WihR, (void*)&WhhR, (void*)&bihR, (void*)&bhhR,
                  (void*)&hbuf, (void*)&cnt, (void*)&outp};
  hipLaunchCooperativeKernel((const void*)bilstm_persistent,
                             dim3(256), dim3(1024), args, 0, stream);
}

// Round 4
// 37174.081 us; speedup vs baseline: 3.9672x; 3.9672x over previous
//
#include <hip/hip_runtime.h>
#include <hip/hip_bf16.h>
#include <math.h>

typedef __attribute__((ext_vector_type(8))) short bf16x8;
typedef __attribute__((ext_vector_type(4))) float f32x4;
typedef __attribute__((ext_vector_type(4))) unsigned u32x4;

namespace {
constexpr int T = 512, B = 64, D = 512, H = 512;
constexpr int NBLK = 128;        // blocks per direction
constexpr int PLANE = B * H;     // bf16 elems per h-plane
constexpr int XPOFF = 4096;      // xP base (floats) in LDS; hP = [0,4096)
}

__global__ __launch_bounds__(64) void ws_init(int* cnt) {
  if (threadIdx.x < 16) cnt[threadIdx.x] = 0;
}

static __device__ __forceinline__ f32x4 mfma16(bf16x8 a, bf16x8 b, f32x4 c) {
  return __builtin_amdgcn_mfma_f32_16x16x32_bf16(a, b, c, 0, 0, 0);
}

// truncation split: v = hi + lo with |err| <~ 2^-16 rel; packs 2 elems/dword
static __device__ __forceinline__ void split2(float v0, float v1,
                                              unsigned& hi, unsigned& lo) {
  unsigned b0 = __builtin_bit_cast(unsigned, v0);
  unsigned b1 = __builtin_bit_cast(unsigned, v1);
  hi = (b0 >> 16) | (b1 & 0xffff0000u);
  float r0 = v0 - __builtin_bit_cast(float, b0 & 0xffff0000u);
  float r1 = v1 - __builtin_bit_cast(float, b1 & 0xffff0000u);
  lo = (__builtin_bit_cast(unsigned, r0) >> 16) |
       (__builtin_bit_cast(unsigned, r1) & 0xffff0000u);
}
static __device__ __forceinline__ void split8(float4 a, float4 b,
                                              bf16x8& hi8, bf16x8& lo8) {
  unsigned h0, h1, h2, h3, l0, l1, l2, l3;
  split2(a.x, a.y, h0, l0); split2(a.z, a.w, h1, l1);
  split2(b.x, b.y, h2, l2); split2(b.z, b.w, h3, l3);
  u32x4 uh = {h0, h1, h2, h3}, ul = {l0, l1, l2, l3};
  hi8 = __builtin_bit_cast(bf16x8, uh);
  lo8 = __builtin_bit_cast(bf16x8, ul);
}

// Persistent bi-LSTM, MFMA bf16x3 (exact to ~2^-16 rel).
// grid=256 (1/CU): dir(2) x jslice(128, 4 j = 16 gate-cols each).
// block=512 = 8 waves: waves 0-3 x-GEMM(step s+1) k-slices, waves 4-7
// h-GEMM(step s) k-slices. W-fragments persist in registers. LDS = partial
// buffers only. Per-direction cumulative atomic barrier.
__global__ __launch_bounds__(512, 2) void bilstm_mfma(
    const float* __restrict__ x, const float* __restrict__ mask,
    const float* __restrict__ WihF, const float* __restrict__ WhhF,
    const float* __restrict__ bihF, const float* __restrict__ bhhF,
    const float* __restrict__ WihR, const float* __restrict__ WhhR,
    const float* __restrict__ bihR, const float* __restrict__ bhhR,
    unsigned short* __restrict__ hpl, int* __restrict__ cnt,
    float* __restrict__ out)
{
  __shared__ float P[XPOFF + 2 * 4096];   // hP[4 waves][1024] + xP[2][4][1024]

  const int tid  = threadIdx.x;
  const int dir  = (int)blockIdx.x >> 7;
  const int j0   = ((int)blockIdx.x & 127) * 4;
  const int wave = tid >> 6, lane = tid & 63;
  const int q = lane >> 4, ln15 = lane & 15;
  const bool is_h = wave >= 4;
  const int wh = wave - 4;

  const float* __restrict__ Wih = dir ? WihR : WihF;
  const float* __restrict__ Whh = dir ? WhhR : WhhF;
  const float* __restrict__ bih = dir ? bihR : bihF;
  const float* __restrict__ bhh = dir ? bhhR : bhhF;

  // B-operand col c = lane&15 -> (jj = c>>2, gate g = c&3)
  const int jj = ln15 >> 2, g = ln15 & 3;

  // ---- W-fragments into registers, once. wave k-slice = 128 k.
  bf16x8 Whi[4], Wlo[4];
  {
    const float* Wm  = is_h ? Whh : Wih;
    const int kb     = (is_h ? wh : wave) * 128;
    const float* wr  = Wm + (size_t)(g * H + j0 + jj) * 512 + kb;
    #pragma unroll
    for (int ks = 0; ks < 4; ++ks) {
      const float* p = wr + ks * 32 + q * 8;
      split8(*(const float4*)p, *(const float4*)(p + 4), Whi[ks], Wlo[ks]);
    }
  }

  // ---- finisher state (tid<256): output (b = tid>>2, j = j0 + (tid&3))
  const int fb = (tid >> 2) & 63, fjj = tid & 3;
  float bs0 = 0.f, bs1 = 0.f, bs2 = 0.f, bs3 = 0.f, cReg = 0.f, hReg = 0.f;
  if (tid < 256) {
    bs0 = bih[0 * H + j0 + fjj] + bhh[0 * H + j0 + fjj];
    bs1 = bih[1 * H + j0 + fjj] + bhh[1 * H + j0 + fjj];
    bs2 = bih[2 * H + j0 + fjj] + bhh[2 * H + j0 + fjj];
    bs3 = bih[3 * H + j0 + fjj] + bhh[3 * H + j0 + fjj];
  }

  auto x_gemm = [&](int t, int par) {
    f32x4 acc[4] = {{0,0,0,0},{0,0,0,0},{0,0,0,0},{0,0,0,0}};
    #pragma unroll
    for (int mt = 0; mt < 4; ++mt) {
      const float* xr = x + ((size_t)t * B + ln15 + 16 * mt) * D + wave * 128 + q * 8;
      #pragma unroll
      for (int ks = 0; ks < 4; ++ks) {
        bf16x8 Ah, Al;
        split8(*(const float4*)(xr + ks * 32),
               *(const float4*)(xr + ks * 32 + 4), Ah, Al);
        acc[mt] = mfma16(Ah, Whi[ks], acc[mt]);
        acc[mt] = mfma16(Ah, Wlo[ks], acc[mt]);
        acc[mt] = mfma16(Al, Whi[ks], acc[mt]);
      }
    }
    float* dst = P + XPOFF + par * 4096 + wave * 1024;
    #pragma unroll
    for (int mt = 0; mt < 4; ++mt)
      #pragma unroll
      for (int r = 0; r < 4; ++r)
        dst[mt * 256 + (q * 4 + r) * 16 + ln15] = acc[mt][r];
  };

  auto h_gemm = [&](int s) {
    const unsigned short* phi =
        hpl + ((size_t)((s & 1) * 2 + dir) * 2) * PLANE;
    const unsigned short* plo = phi + PLANE;
    f32x4 acc[4] = {{0,0,0,0},{0,0,0,0},{0,0,0,0},{0,0,0,0}};
    #pragma unroll
    for (int mt = 0; mt < 4; ++mt) {
      const size_t base = (size_t)(ln15 + 16 * mt) * H + wh * 128 + q * 8;
      #pragma unroll
      for (int ks = 0; ks < 4; ++ks) {
        bf16x8 Ah = *(const bf16x8*)(phi + base + ks * 32);
        bf16x8 Al = *(const bf16x8*)(plo + base + ks * 32);
        acc[mt] = mfma16(Ah, Whi[ks], acc[mt]);
        acc[mt] = mfma16(Ah, Wlo[ks], acc[mt]);
        acc[mt] = mfma16(Al, Whi[ks], acc[mt]);
      }
    }
    float* dst = P + wh * 1024;
    #pragma unroll
    for (int mt = 0; mt < 4; ++mt)
      #pragma unroll
      for (int r = 0; r < 4; ++r)
        dst[mt * 256 + (q * 4 + r) * 16 + ln15] = acc[mt][r];
  };

  // ---- prologue: h-waves zero hP (h(0)=0 => zero partials); x-waves do x(t0)
  if (is_h) {
    for (int i = tid - 256; i < 4096; i += 256) P[i] = 0.f;
  } else {
    x_gemm(dir ? (T - 1) : 0, 0);
  }

  for (int s = 0; s < T; ++s) {
    // ---- GEMM phase (wave-specialized)
    if (is_h) {
      if (s > 0) {
        const int target = NBLK * s;   // all finishers of step s-1 arrived
        while (__hip_atomic_load(&cnt[dir], __ATOMIC_RELAXED,
                                 __HIP_MEMORY_SCOPE_AGENT) < target)
          __builtin_amdgcn_s_sleep(2);
        __threadfence();               // acquire: fresh h planes
        h_gemm(s);
      }
    } else {
      if (s + 1 < T) x_gemm(dir ? (T - 2 - s) : (s + 1), (s + 1) & 1);
    }
    __syncthreads();

    // ---- finisher
    if (tid < 256) {
      const int t = dir ? (T - 1 - s) : s;
      const float mval = mask[(size_t)t * B + fb];
      const int off = (fb >> 4) * 256 + (fb & 15) * 16 + fjj * 4;
      const float* xPr = P + XPOFF + (s & 1) * 4096;
      f32x4 sum = {bs0, bs1, bs2, bs3};
      #pragma unroll
      for (int w = 0; w < 4; ++w) {
        sum += *(const f32x4*)(P + w * 1024 + off);     // h partials
        sum += *(const f32x4*)(xPr + w * 1024 + off);   // x partials
      }
      const float ig = 1.f / (1.f + expf(-sum[0]));
      const float fg = 1.f / (1.f + expf(-sum[1]));
      const float gg = tanhf(sum[2]);
      const float og = 1.f / (1.f + expf(-sum[3]));
      const float cNew = fg * cReg + ig * gg;
      const float hNew = og * tanhf(cNew);
      hReg = hNew * mval + hReg * (1.f - mval);
      cReg = cNew * mval + cReg * (1.f - mval);

      // h -> bf16 hi/lo planes of buffer (s+1)&1, fragment-order layout
      unsigned hb = __builtin_bit_cast(unsigned, hReg);
      unsigned short hhi = (unsigned short)(hb >> 16);
      float rres = hReg - __builtin_bit_cast(float, hb & 0xffff0000u);
      unsigned short hlo =
          (unsigned short)(__builtin_bit_cast(unsigned, rres) >> 16);
      unsigned short* nh =
          hpl + ((size_t)((((s + 1) & 1) * 2 + dir)) * 2) * PLANE +
          (size_t)fb * H + j0 + fjj;
      nh[0] = hhi;
      nh[PLANE] = hlo;
      out[((size_t)t * B + fb) * (2 * H) + (size_t)dir * H + j0 + fjj] = hReg;
      __threadfence();                 // release h before arrive
    }
    __syncthreads();
    if (tid == 0 && s + 1 < T) atomicAdd(&cnt[dir], 1);
  }
}

extern "C" void kernel_launch(void* const* d_in, const int* in_sizes, int n_in,
                              void* d_out, int out_size, void* d_ws, size_t ws_size,
                              hipStream_t stream) {
  const float* x    = (const float*)d_in[0];
  const float* mask = (const float*)d_in[1];
  const float* WihF = (const float*)d_in[2];
  const float* WhhF = (const float*)d_in[3];
  const float* bihF = (const float*)d_in[4];
  const float* bhhF = (const float*)d_in[5];
  const float* WihR = (const float*)d_in[6];
  const float* WhhR = (const float*)d_in[7];
  const float* bihR = (const float*)d_in[8];
  const float* bhhR = (const float*)d_in[9];
  float* outp = (float*)d_out;

  int* cnt = (int*)d_ws;                               // 16 ints
  unsigned short* hpl = (unsigned short*)((char*)d_ws + 64);  // 8 planes x 64 KB

  ws_init<<<1, 64, 0, stream>>>(cnt);

  void* args[] = {(void*)&x, (void*)&mask,
                  (void*)&WihF, (void*)&WhhF, (void*)&bihF, (void*)&bhhF,
                  (void*)&WihR, (void*)&WhhR, (void*)&bihR, (void*)&bhhR,
                  (void*)&hpl, (void*)&cnt, (void*)&outp};
  hipLaunchCooperativeKernel((const void*)bilstm_mfma,
                             dim3(256), dim3(512), args, 0, stream);
}